// Round 1
// baseline (284.333 us; speedup 1.0000x reference)
//
#include <hip/hip_runtime.h>
#include <hip/hip_bf16.h>

#define IN_DIM 128
#define HID_DIM 64
#define OUT_DIM 16

// ---------------------------------------------------------------------------
// Utility: zero the count array
// ---------------------------------------------------------------------------
__global__ void zero_cnt_kernel(int* __restrict__ cnt, int N) {
    int i = blockIdx.x * blockDim.x + threadIdx.x;
    if (i < N) cnt[i] = 0;
}

// ---------------------------------------------------------------------------
// Histogram of dst (in-degree, excluding self loop)
// ---------------------------------------------------------------------------
__global__ void hist_kernel(const int* __restrict__ dst, int* __restrict__ cnt, int E) {
    int i = blockIdx.x * blockDim.x + threadIdx.x;
    if (i < E) atomicAdd(&cnt[dst[i]], 1);
}

// ---------------------------------------------------------------------------
// Prefix scan (3-phase). Block size 256.  Phase A: per-block exclusive scan.
// ---------------------------------------------------------------------------
__global__ void scanA_kernel(const int* __restrict__ cnt, int* __restrict__ part,
                             int* __restrict__ blockSums, int N) {
    __shared__ int s[256];
    int t = threadIdx.x;
    int i = blockIdx.x * 256 + t;
    int v = (i < N) ? cnt[i] : 0;
    s[t] = v;
    __syncthreads();
    for (int off = 1; off < 256; off <<= 1) {
        int tmp = (t >= off) ? s[t - off] : 0;
        __syncthreads();
        s[t] += tmp;
        __syncthreads();
    }
    if (i < N) part[i] = s[t] - v;               // exclusive within block
    if (t == 255) blockSums[blockIdx.x] = s[255]; // block total
}

// Phase B: exclusive scan of block sums (nb <= 256, single block)
__global__ void scanB_kernel(int* __restrict__ blockSums, int nb) {
    __shared__ int s[256];
    int t = threadIdx.x;
    int v = (t < nb) ? blockSums[t] : 0;
    s[t] = v;
    __syncthreads();
    for (int off = 1; off < 256; off <<= 1) {
        int tmp = (t >= off) ? s[t - off] : 0;
        __syncthreads();
        s[t] += tmp;
        __syncthreads();
    }
    if (t < nb) blockSums[t] = s[t] - v;          // exclusive block offsets
}

// Phase C: add block offsets, init cursor, compute dinv = rsqrt(deg)
__global__ void scanC_kernel(int* __restrict__ row_ptr, const int* __restrict__ blockSums,
                             const int* __restrict__ cnt, int* __restrict__ cursor,
                             float* __restrict__ dinv, int N, int E) {
    int i = blockIdx.x * 256 + threadIdx.x;
    if (i < N) {
        int rp = row_ptr[i] + blockSums[blockIdx.x];
        row_ptr[i] = rp;
        cursor[i]  = rp;
        dinv[i]    = rsqrtf((float)(cnt[i] + 1));  // +1 self loop; always > 0
    }
    if (i == 0) row_ptr[N] = E;
}

// ---------------------------------------------------------------------------
// Fill CSR: csr_src grouped by dst
// ---------------------------------------------------------------------------
__global__ void fill_kernel(const int* __restrict__ src, const int* __restrict__ dst,
                            int* __restrict__ cursor, int* __restrict__ csr_src, int E) {
    int i = blockIdx.x * blockDim.x + threadIdx.x;
    if (i < E) {
        int d = dst[i];
        int pos = atomicAdd(&cursor[d], 1);
        csr_src[pos] = src[i];
    }
}

// ---------------------------------------------------------------------------
// GEMM1: h1 = x @ W1   [N,128] @ [128,64]
// 16 nodes per block, 256 threads: thread = (node_ln 0..15, col-group jj 0..15 of 4 cols)
// ---------------------------------------------------------------------------
__global__ __launch_bounds__(256) void gemm1_kernel(const float* __restrict__ x,
                                                    const float* __restrict__ W1,
                                                    float* __restrict__ h1, int N) {
    __shared__ __align__(16) float sW[IN_DIM * HID_DIM];   // 32 KB
    __shared__ __align__(16) float sx[16 * IN_DIM];        // 8 KB
    int t = threadIdx.x;
    int node0 = blockIdx.x * 16;

    const float4* W4  = (const float4*)W1;
    float4*       sW4 = (float4*)sW;
    for (int i = t; i < (IN_DIM * HID_DIM) / 4; i += 256) sW4[i] = W4[i];

    const float4* x4  = (const float4*)x;
    float4*       sx4 = (float4*)sx;
    for (int i = t; i < (16 * IN_DIM) / 4; i += 256) {
        int r = i >> 5, c = i & 31;             // 32 float4 per row of 128
        int n = node0 + r; if (n >= N) n = 0;   // clamp (avoid OOB read)
        sx4[(r << 5) + c] = x4[(size_t)n * 32 + c];
    }
    __syncthreads();

    int ln = t >> 4, jj = t & 15;
    int n = node0 + ln;
    float4 acc = {0.f, 0.f, 0.f, 0.f};
    const float* xr = sx + ln * IN_DIM;
    #pragma unroll 4
    for (int k = 0; k < IN_DIM; ++k) {
        float  xk = xr[k];
        float4 wv = ((const float4*)(sW + k * HID_DIM))[jj];
        acc.x += xk * wv.x; acc.y += xk * wv.y; acc.z += xk * wv.z; acc.w += xk * wv.w;
    }
    if (n < N) ((float4*)(h1 + (size_t)n * HID_DIM))[jj] = acc;
}

// ---------------------------------------------------------------------------
// Aggregation layer 1: one wave (64 lanes = 64 dims) per node; 4 nodes/block.
// out = relu( sum_{e: dst=n} h1[src]*dinv[src]*dinv[n] + h1[n]*dinv[n]^2 + b1 )
// ---------------------------------------------------------------------------
__global__ __launch_bounds__(256) void agg1_kernel(const float* __restrict__ h1,
                                                   const int* __restrict__ row_ptr,
                                                   const int* __restrict__ csr_src,
                                                   const float* __restrict__ dinv,
                                                   const float* __restrict__ b1,
                                                   float* __restrict__ h1a, int N) {
    int t = threadIdx.x;
    int n = blockIdx.x * 4 + (t >> 6);
    int d = t & 63;
    if (n >= N) return;
    float dn  = dinv[n];
    float acc = h1[(size_t)n * HID_DIM + d] * (dn * dn);   // self loop
    int e0 = row_ptr[n], e1 = row_ptr[n + 1];
    int e = e0;
    for (; e + 3 < e1; e += 4) {                            // 4-wide for MLP
        int s0 = csr_src[e], s1 = csr_src[e + 1], s2 = csr_src[e + 2], s3 = csr_src[e + 3];
        float w0 = dinv[s0], w1 = dinv[s1], w2 = dinv[s2], w3 = dinv[s3];
        float v0 = h1[(size_t)s0 * HID_DIM + d];
        float v1 = h1[(size_t)s1 * HID_DIM + d];
        float v2 = h1[(size_t)s2 * HID_DIM + d];
        float v3 = h1[(size_t)s3 * HID_DIM + d];
        acc += v0 * (w0 * dn) + v1 * (w1 * dn) + v2 * (w2 * dn) + v3 * (w3 * dn);
    }
    for (; e < e1; ++e) {
        int s = csr_src[e];
        acc += h1[(size_t)s * HID_DIM + d] * (dinv[s] * dn);
    }
    h1a[(size_t)n * HID_DIM + d] = fmaxf(acc + b1[d], 0.0f);
}

// ---------------------------------------------------------------------------
// GEMM2: h2 = h1a @ W2   [N,64] @ [64,16]
// ---------------------------------------------------------------------------
__global__ __launch_bounds__(256) void gemm2_kernel(const float* __restrict__ h1a,
                                                    const float* __restrict__ W2,
                                                    float* __restrict__ h2, int N) {
    __shared__ __align__(16) float sW[HID_DIM * OUT_DIM];  // 4 KB
    __shared__ __align__(16) float sx[16 * HID_DIM];       // 4 KB
    int t = threadIdx.x;
    int node0 = blockIdx.x * 16;

    ((float4*)sW)[t] = ((const float4*)W2)[t];             // 256 float4 = 1024 floats
    {
        int r = t >> 4, c = t & 15;                        // 16 float4 per row of 64
        int n = node0 + r; if (n >= N) n = 0;
        ((float4*)sx)[(r << 4) + c] = ((const float4*)h1a)[(size_t)n * 16 + c];
    }
    __syncthreads();

    int ln = t >> 4, j = t & 15;
    float acc = 0.f;
    const float* xr = sx + ln * HID_DIM;
    #pragma unroll 8
    for (int k = 0; k < HID_DIM; ++k) acc += xr[k] * sW[k * OUT_DIM + j];
    int n = node0 + ln;
    if (n < N) h2[(size_t)n * OUT_DIM + j] = acc;
}

// ---------------------------------------------------------------------------
// Aggregation layer 2: 16 lanes per node (4 nodes/wave, 16 nodes/block).
// out = sum msg + self + b2   (written directly to d_out)
// ---------------------------------------------------------------------------
__global__ __launch_bounds__(256) void agg2_kernel(const float* __restrict__ h2,
                                                   const int* __restrict__ row_ptr,
                                                   const int* __restrict__ csr_src,
                                                   const float* __restrict__ dinv,
                                                   const float* __restrict__ b2,
                                                   float* __restrict__ out, int N) {
    int t = threadIdx.x;
    int n = blockIdx.x * 16 + (t >> 4);
    int d = t & 15;
    if (n >= N) return;
    float dn  = dinv[n];
    float acc = h2[(size_t)n * OUT_DIM + d] * (dn * dn);   // self loop
    int e0 = row_ptr[n], e1 = row_ptr[n + 1];
    int e = e0;
    for (; e + 3 < e1; e += 4) {
        int s0 = csr_src[e], s1 = csr_src[e + 1], s2 = csr_src[e + 2], s3 = csr_src[e + 3];
        float w0 = dinv[s0], w1 = dinv[s1], w2 = dinv[s2], w3 = dinv[s3];
        acc += h2[(size_t)s0 * OUT_DIM + d] * (w0 * dn)
             + h2[(size_t)s1 * OUT_DIM + d] * (w1 * dn)
             + h2[(size_t)s2 * OUT_DIM + d] * (w2 * dn)
             + h2[(size_t)s3 * OUT_DIM + d] * (w3 * dn);
    }
    for (; e < e1; ++e) {
        int s = csr_src[e];
        acc += h2[(size_t)s * OUT_DIM + d] * (dinv[s] * dn);
    }
    out[(size_t)n * OUT_DIM + d] = acc + b2[d];
}

// ---------------------------------------------------------------------------
// Launch
// ---------------------------------------------------------------------------
extern "C" void kernel_launch(void* const* d_in, const int* in_sizes, int n_in,
                              void* d_out, int out_size, void* d_ws, size_t ws_size,
                              hipStream_t stream) {
    const float* x  = (const float*)d_in[0];
    const int*   ei = (const int*)d_in[1];
    const float* W1 = (const float*)d_in[2];
    const float* b1 = (const float*)d_in[3];
    const float* W2 = (const float*)d_in[4];
    const float* b2 = (const float*)d_in[5];
    float* out = (float*)d_out;

    const int N = in_sizes[0] / IN_DIM;   // 50000
    const int E = in_sizes[1] / 2;        // 1000000
    const int* src = ei;
    const int* dst = ei + E;

    // Workspace layout (256 B aligned slices)
    char* w = (char*)d_ws;
    auto alloc = [&](size_t bytes) -> void* {
        void* p = (void*)w;
        w += (bytes + 255) & ~(size_t)255;
        return p;
    };
    int*   cnt       = (int*)  alloc((size_t)N * 4);
    int*   row_ptr   = (int*)  alloc((size_t)(N + 1) * 4);
    int*   cursor    = (int*)  alloc((size_t)N * 4);
    int*   blockSums = (int*)  alloc(1024);
    float* dinv      = (float*)alloc((size_t)N * 4);
    int*   csr_src   = (int*)  alloc((size_t)E * 4);
    float* h1        = (float*)alloc((size_t)N * HID_DIM * 4);
    float* h1a       = (float*)alloc((size_t)N * HID_DIM * 4);
    float* h2        = (float*)alloc((size_t)N * OUT_DIM * 4);

    const int NB  = (N + 255) / 256;      // 196 scan blocks (must be <= 256)
    const int EB  = (E + 255) / 256;      // edge-parallel blocks
    const int GB  = (N + 15) / 16;        // 16-nodes-per-block grids

    zero_cnt_kernel<<<NB, 256, 0, stream>>>(cnt, N);
    hist_kernel<<<EB, 256, 0, stream>>>(dst, cnt, E);
    scanA_kernel<<<NB, 256, 0, stream>>>(cnt, row_ptr, blockSums, N);
    scanB_kernel<<<1, 256, 0, stream>>>(blockSums, NB);
    scanC_kernel<<<NB, 256, 0, stream>>>(row_ptr, blockSums, cnt, cursor, dinv, N, E);
    fill_kernel<<<EB, 256, 0, stream>>>(src, dst, cursor, csr_src, E);

    gemm1_kernel<<<GB, 256, 0, stream>>>(x, W1, h1, N);
    agg1_kernel<<<(N + 3) / 4, 256, 0, stream>>>(h1, row_ptr, csr_src, dinv, b1, h1a, N);
    gemm2_kernel<<<GB, 256, 0, stream>>>(h1a, W2, h2, N);
    agg2_kernel<<<GB, 256, 0, stream>>>(h2, row_ptr, csr_src, dinv, b2, out, N);
}

// Round 2
// 266.254 us; speedup vs baseline: 1.0679x; 1.0679x over previous
//
#include <hip/hip_runtime.h>
#include <hip/hip_bf16.h>

#define IN_DIM 128
#define HID_DIM 64
#define OUT_DIM 16

// ---------------------------------------------------------------------------
// Histogram of dst (in-degree, excluding self loop)
// ---------------------------------------------------------------------------
__global__ void hist_kernel(const int* __restrict__ dst, int* __restrict__ cnt, int E) {
    int i = blockIdx.x * blockDim.x + threadIdx.x;
    if (i < E) atomicAdd(&cnt[dst[i]], 1);
}

// ---------------------------------------------------------------------------
// Prefix scan (3-phase). Block size 256.  Phase A: per-block exclusive scan.
// ---------------------------------------------------------------------------
__global__ void scanA_kernel(const int* __restrict__ cnt, int* __restrict__ part,
                             int* __restrict__ blockSums, int N) {
    __shared__ int s[256];
    int t = threadIdx.x;
    int i = blockIdx.x * 256 + t;
    int v = (i < N) ? cnt[i] : 0;
    s[t] = v;
    __syncthreads();
    for (int off = 1; off < 256; off <<= 1) {
        int tmp = (t >= off) ? s[t - off] : 0;
        __syncthreads();
        s[t] += tmp;
        __syncthreads();
    }
    if (i < N) part[i] = s[t] - v;               // exclusive within block
    if (t == 255) blockSums[blockIdx.x] = s[255]; // block total
}

// Phase B: exclusive scan of block sums (nb <= 256, single block)
__global__ void scanB_kernel(int* __restrict__ blockSums, int nb) {
    __shared__ int s[256];
    int t = threadIdx.x;
    int v = (t < nb) ? blockSums[t] : 0;
    s[t] = v;
    __syncthreads();
    for (int off = 1; off < 256; off <<= 1) {
        int tmp = (t >= off) ? s[t - off] : 0;
        __syncthreads();
        s[t] += tmp;
        __syncthreads();
    }
    if (t < nb) blockSums[t] = s[t] - v;          // exclusive block offsets
}

// Phase C: add block offsets, init cursor, compute dinv = rsqrt(deg)
__global__ void scanC_kernel(int* __restrict__ row_ptr, const int* __restrict__ blockSums,
                             const int* __restrict__ cnt, int* __restrict__ cursor,
                             float* __restrict__ dinv, int N, int E) {
    int i = blockIdx.x * 256 + threadIdx.x;
    if (i < N) {
        int rp = row_ptr[i] + blockSums[blockIdx.x];
        row_ptr[i] = rp;
        cursor[i]  = rp;
        dinv[i]    = rsqrtf((float)(cnt[i] + 1));  // +1 self loop; always > 0
    }
    if (i == 0) row_ptr[N] = E;
}

// ---------------------------------------------------------------------------
// Fill CSR, XCD-partitioned: block b scans edge chunk (b>>3) but only commits
// edges whose dst group (dst/3125)&7 == (b&7). With round-robin workgroup->XCD
// dispatch, all writes to a given csr_src stripe come from ONE XCD's L2, so
// lines merge fully before write-back (67 MB -> ~4-8 MB HBM writes).
// 16 stripes of 3125 nodes; group r owns stripes {r, r+8}.
// ---------------------------------------------------------------------------
__global__ __launch_bounds__(256) void fill_kernel(const int* __restrict__ src,
                                                   const int* __restrict__ dst,
                                                   int* __restrict__ cursor,
                                                   int* __restrict__ csr_src, int E) {
    int r = blockIdx.x & 7;
    int i = (blockIdx.x >> 3) * 256 + threadIdx.x;
    if (i >= E) return;
    int d = dst[i];
    int g = (int)((unsigned)d / 3125u) & 7;
    if (g != r) return;
    int pos = atomicAdd(&cursor[d], 1);
    csr_src[pos] = src[i];
}

// ---------------------------------------------------------------------------
// GEMM1: h1 = (x @ W1) * dinv[n]   [N,128] @ [128,64], dinv folded in epilogue
// 16 nodes per block, 256 threads: thread = (node_ln 0..15, col-group jj 0..15 of 4 cols)
// ---------------------------------------------------------------------------
__global__ __launch_bounds__(256) void gemm1_kernel(const float* __restrict__ x,
                                                    const float* __restrict__ W1,
                                                    const float* __restrict__ dinv,
                                                    float* __restrict__ h1, int N) {
    __shared__ __align__(16) float sW[IN_DIM * HID_DIM];   // 32 KB
    __shared__ __align__(16) float sx[16 * IN_DIM];        // 8 KB
    int t = threadIdx.x;
    int node0 = blockIdx.x * 16;

    const float4* W4  = (const float4*)W1;
    float4*       sW4 = (float4*)sW;
    for (int i = t; i < (IN_DIM * HID_DIM) / 4; i += 256) sW4[i] = W4[i];

    const float4* x4  = (const float4*)x;
    float4*       sx4 = (float4*)sx;
    for (int i = t; i < (16 * IN_DIM) / 4; i += 256) {
        int r = i >> 5, c = i & 31;             // 32 float4 per row of 128
        int n = node0 + r; if (n >= N) n = 0;   // clamp (avoid OOB read)
        sx4[(r << 5) + c] = x4[(size_t)n * 32 + c];
    }
    __syncthreads();

    int ln = t >> 4, jj = t & 15;
    int n = node0 + ln;
    float4 acc = {0.f, 0.f, 0.f, 0.f};
    const float* xr = sx + ln * IN_DIM;
    #pragma unroll 4
    for (int k = 0; k < IN_DIM; ++k) {
        float  xk = xr[k];
        float4 wv = ((const float4*)(sW + k * HID_DIM))[jj];
        acc.x += xk * wv.x; acc.y += xk * wv.y; acc.z += xk * wv.z; acc.w += xk * wv.w;
    }
    if (n < N) {
        float dn = dinv[n];
        acc.x *= dn; acc.y *= dn; acc.z *= dn; acc.w *= dn;
        ((float4*)(h1 + (size_t)n * HID_DIM))[jj] = acc;
    }
}

// ---------------------------------------------------------------------------
// Aggregation layer 1: one wave (64 lanes = 64 dims) per node; 4 nodes/block.
// h1 rows are pre-scaled by dinv[src], so:
// out = relu( dinv[n] * ( h1[n] + sum_{e} h1[src] ) + b1 )
// (self-loop term h1[n]*dinv[n]^2 == dinv[n] * h1'[n] with h1' pre-scaled)
// ---------------------------------------------------------------------------
__global__ __launch_bounds__(256) void agg1_kernel(const float* __restrict__ h1,
                                                   const int* __restrict__ row_ptr,
                                                   const int* __restrict__ csr_src,
                                                   const float* __restrict__ dinv,
                                                   const float* __restrict__ b1,
                                                   float* __restrict__ h1a, int N) {
    int t = threadIdx.x;
    int n = blockIdx.x * 4 + (t >> 6);
    int d = t & 63;
    if (n >= N) return;
    float acc0 = h1[(size_t)n * HID_DIM + d];   // self loop (pre-scaled)
    float acc1 = 0.f, acc2 = 0.f, acc3 = 0.f;
    int e0 = row_ptr[n], e1 = row_ptr[n + 1];
    int e = e0;
    for (; e + 3 < e1; e += 4) {
        int s0 = csr_src[e], s1 = csr_src[e + 1], s2 = csr_src[e + 2], s3 = csr_src[e + 3];
        acc0 += h1[(size_t)s0 * HID_DIM + d];
        acc1 += h1[(size_t)s1 * HID_DIM + d];
        acc2 += h1[(size_t)s2 * HID_DIM + d];
        acc3 += h1[(size_t)s3 * HID_DIM + d];
    }
    for (; e < e1; ++e) acc1 += h1[(size_t)csr_src[e] * HID_DIM + d];
    float acc = (acc0 + acc1) + (acc2 + acc3);
    h1a[(size_t)n * HID_DIM + d] = fmaxf(dinv[n] * acc + b1[d], 0.0f);
}

// ---------------------------------------------------------------------------
// GEMM2: h2 = (h1a @ W2) * dinv[n]   [N,64] @ [64,16]
// ---------------------------------------------------------------------------
__global__ __launch_bounds__(256) void gemm2_kernel(const float* __restrict__ h1a,
                                                    const float* __restrict__ W2,
                                                    const float* __restrict__ dinv,
                                                    float* __restrict__ h2, int N) {
    __shared__ __align__(16) float sW[HID_DIM * OUT_DIM];  // 4 KB
    __shared__ __align__(16) float sx[16 * HID_DIM];       // 4 KB
    int t = threadIdx.x;
    int node0 = blockIdx.x * 16;

    ((float4*)sW)[t] = ((const float4*)W2)[t];             // 256 float4 = 1024 floats
    {
        int r = t >> 4, c = t & 15;                        // 16 float4 per row of 64
        int n = node0 + r; if (n >= N) n = 0;
        ((float4*)sx)[(r << 4) + c] = ((const float4*)h1a)[(size_t)n * 16 + c];
    }
    __syncthreads();

    int ln = t >> 4, j = t & 15;
    float acc = 0.f;
    const float* xr = sx + ln * HID_DIM;
    #pragma unroll 8
    for (int k = 0; k < HID_DIM; ++k) acc += xr[k] * sW[k * OUT_DIM + j];
    int n = node0 + ln;
    if (n < N) h2[(size_t)n * OUT_DIM + j] = acc * dinv[n];
}

// ---------------------------------------------------------------------------
// Aggregation layer 2: 16 lanes per node (4 nodes/wave, 16 nodes/block).
// h2 pre-scaled by dinv[src]; out = dinv[n]*(h2[n] + sum h2[src]) + b2
// ---------------------------------------------------------------------------
__global__ __launch_bounds__(256) void agg2_kernel(const float* __restrict__ h2,
                                                   const int* __restrict__ row_ptr,
                                                   const int* __restrict__ csr_src,
                                                   const float* __restrict__ dinv,
                                                   const float* __restrict__ b2,
                                                   float* __restrict__ out, int N) {
    int t = threadIdx.x;
    int n = blockIdx.x * 16 + (t >> 4);
    int d = t & 15;
    if (n >= N) return;
    float acc0 = h2[(size_t)n * OUT_DIM + d];   // self loop (pre-scaled)
    float acc1 = 0.f, acc2 = 0.f, acc3 = 0.f;
    int e0 = row_ptr[n], e1 = row_ptr[n + 1];
    int e = e0;
    for (; e + 3 < e1; e += 4) {
        int s0 = csr_src[e], s1 = csr_src[e + 1], s2 = csr_src[e + 2], s3 = csr_src[e + 3];
        acc0 += h2[(size_t)s0 * OUT_DIM + d];
        acc1 += h2[(size_t)s1 * OUT_DIM + d];
        acc2 += h2[(size_t)s2 * OUT_DIM + d];
        acc3 += h2[(size_t)s3 * OUT_DIM + d];
    }
    for (; e < e1; ++e) acc1 += h2[(size_t)csr_src[e] * OUT_DIM + d];
    float acc = (acc0 + acc1) + (acc2 + acc3);
    out[(size_t)n * OUT_DIM + d] = dinv[n] * acc + b2[d];
}

// ---------------------------------------------------------------------------
// Launch
// ---------------------------------------------------------------------------
extern "C" void kernel_launch(void* const* d_in, const int* in_sizes, int n_in,
                              void* d_out, int out_size, void* d_ws, size_t ws_size,
                              hipStream_t stream) {
    const float* x  = (const float*)d_in[0];
    const int*   ei = (const int*)d_in[1];
    const float* W1 = (const float*)d_in[2];
    const float* b1 = (const float*)d_in[3];
    const float* W2 = (const float*)d_in[4];
    const float* b2 = (const float*)d_in[5];
    float* out = (float*)d_out;

    const int N = in_sizes[0] / IN_DIM;   // 50000
    const int E = in_sizes[1] / 2;        // 1000000
    const int* src = ei;
    const int* dst = ei + E;

    // Workspace layout (256 B aligned slices)
    char* w = (char*)d_ws;
    auto alloc = [&](size_t bytes) -> void* {
        void* p = (void*)w;
        w += (bytes + 255) & ~(size_t)255;
        return p;
    };
    int*   cnt       = (int*)  alloc((size_t)N * 4);
    int*   row_ptr   = (int*)  alloc((size_t)(N + 1) * 4);
    int*   cursor    = (int*)  alloc((size_t)N * 4);
    int*   blockSums = (int*)  alloc(1024);
    float* dinv      = (float*)alloc((size_t)N * 4);
    int*   csr_src   = (int*)  alloc((size_t)E * 4);
    float* h1        = (float*)alloc((size_t)N * HID_DIM * 4);
    float* h1a       = (float*)alloc((size_t)N * HID_DIM * 4);
    float* h2        = (float*)alloc((size_t)N * OUT_DIM * 4);

    const int NB  = (N + 255) / 256;      // 196 scan blocks (must be <= 256)
    const int EB  = (E + 255) / 256;      // edge-parallel blocks
    const int GB  = (N + 15) / 16;        // 16-nodes-per-block grids

    hipMemsetAsync(cnt, 0, (size_t)N * 4, stream);
    hist_kernel<<<EB, 256, 0, stream>>>(dst, cnt, E);
    scanA_kernel<<<NB, 256, 0, stream>>>(cnt, row_ptr, blockSums, N);
    scanB_kernel<<<1, 256, 0, stream>>>(blockSums, NB);
    scanC_kernel<<<NB, 256, 0, stream>>>(row_ptr, blockSums, cnt, cursor, dinv, N, E);
    fill_kernel<<<EB * 8, 256, 0, stream>>>(src, dst, cursor, csr_src, E);

    gemm1_kernel<<<GB, 256, 0, stream>>>(x, W1, dinv, h1, N);
    agg1_kernel<<<(N + 3) / 4, 256, 0, stream>>>(h1, row_ptr, csr_src, dinv, b1, h1a, N);
    gemm2_kernel<<<GB, 256, 0, stream>>>(h1a, W2, dinv, h2, N);
    agg2_kernel<<<GB, 256, 0, stream>>>(h2, row_ptr, csr_src, dinv, b2, out, N);
}

// Round 3
// 206.792 us; speedup vs baseline: 1.3750x; 1.2875x over previous
//
#include <hip/hip_runtime.h>
#include <hip/hip_bf16.h>

#define IN_DIM 128
#define HID_DIM 64
#define OUT_DIM 16

// Stripe/bin geometry: 128 nodes per stripe
#define SSHIFT 7
#define SMASK 127
// Edge chunking for passes A/C
#define CHUNK 16384
#define CBLK 1024

// ---------------------------------------------------------------------------
// passA: per-block per-stripe histogram (LDS only, no global atomics)
// cm[b * NSP + s] = #edges in block-b's chunk whose dst is in stripe s
// ---------------------------------------------------------------------------
__global__ __launch_bounds__(CBLK) void passA(const int* __restrict__ dst,
                                              int* __restrict__ cm,
                                              int E, int NS, int NSP) {
    __shared__ int cnt[512];
    int t = threadIdx.x;
    for (int s = t; s < NS; s += CBLK) cnt[s] = 0;
    __syncthreads();
    int base = blockIdx.x * CHUNK;
    #pragma unroll 4
    for (int k = 0; k < CHUNK; k += CBLK) {
        int i = base + k + t;
        if (i < E) atomicAdd(&cnt[dst[i] >> SSHIFT], 1);
    }
    __syncthreads();
    for (int s = t; s < NS; s += CBLK) cm[blockIdx.x * NSP + s] = cnt[s];
}

// ---------------------------------------------------------------------------
// passB1: for each stripe s, exclusive scan cm[0..B)[s] in place; tot[s]=sum.
// One 64-thread block per stripe (B <= 64).
// ---------------------------------------------------------------------------
__global__ __launch_bounds__(64) void passB1(int* __restrict__ cm, int* __restrict__ tot,
                                             int B, int NSP) {
    __shared__ int sv[64];
    int t = threadIdx.x, s = blockIdx.x;
    int v = (t < B) ? cm[t * NSP + s] : 0;
    sv[t] = v;
    __syncthreads();
    for (int off = 1; off < 64; off <<= 1) {
        int tmp = (t >= off) ? sv[t - off] : 0;
        __syncthreads();
        sv[t] += tmp;
        __syncthreads();
    }
    if (t < B) cm[t * NSP + s] = sv[t] - v;   // exclusive within stripe
    if (t == 63) tot[s] = sv[63];
}

// ---------------------------------------------------------------------------
// passB2: exclusive scan of stripe totals -> stripe base offsets (NS <= 512)
// ---------------------------------------------------------------------------
__global__ __launch_bounds__(512) void passB2(const int* __restrict__ tot,
                                              int* __restrict__ sbase, int NS) {
    __shared__ int sv[512];
    int t = threadIdx.x;
    int v = (t < NS) ? tot[t] : 0;
    sv[t] = v;
    __syncthreads();
    for (int off = 1; off < 512; off <<= 1) {
        int tmp = (t >= off) ? sv[t - off] : 0;
        __syncthreads();
        sv[t] += tmp;
        __syncthreads();
    }
    if (t < NS) sbase[t] = sv[t] - v;
}

// ---------------------------------------------------------------------------
// passC: bucket edges by stripe. LDS cursors (init from cm + sbase), write
// packed (dl<<17)|src. Runs per (block,stripe) ~41 edges -> near-full lines.
// ---------------------------------------------------------------------------
__global__ __launch_bounds__(CBLK) void passC(const int* __restrict__ src,
                                              const int* __restrict__ dst,
                                              const int* __restrict__ cm,
                                              const int* __restrict__ sbase,
                                              int* __restrict__ eb,
                                              int E, int NS, int NSP) {
    __shared__ int cur[512];
    int t = threadIdx.x, b = blockIdx.x;
    for (int s = t; s < NS; s += CBLK) cur[s] = sbase[s] + cm[b * NSP + s];
    __syncthreads();
    int base = b * CHUNK;
    #pragma unroll 4
    for (int k = 0; k < CHUNK; k += CBLK) {
        int i = base + k + t;
        if (i < E) {
            int d = dst[i];
            int s = d >> SSHIFT;
            int pos = atomicAdd(&cur[s], 1);
            eb[pos] = src[i] | ((d & SMASK) << 17);
        }
    }
}

// ---------------------------------------------------------------------------
// passD: per-stripe LDS counting sort -> exact CSR + row_ptr + dinv.
// Each stripe's csr region written by exactly one block (full-line merge).
// ---------------------------------------------------------------------------
__global__ __launch_bounds__(256) void passD(const int* __restrict__ eb,
                                             const int* __restrict__ sbase,
                                             const int* __restrict__ tot,
                                             int* __restrict__ csr_src,
                                             int* __restrict__ row_ptr,
                                             float* __restrict__ dinv,
                                             int N, int E, int NS) {
    __shared__ int deg[128], incl[128], cur[128];
    int s = blockIdx.x, t = threadIdx.x;
    if (t < 128) deg[t] = 0;
    __syncthreads();
    int b0 = sbase[s], cnt = tot[s];
    for (int k = t; k < cnt; k += 256) atomicAdd(&deg[eb[b0 + k] >> 17], 1);
    __syncthreads();
    if (t < 128) incl[t] = deg[t];
    __syncthreads();
    for (int off = 1; off < 128; off <<= 1) {
        int tmp = 0;
        if (t < 128 && t >= off) tmp = incl[t - off];
        __syncthreads();
        if (t < 128) incl[t] += tmp;
        __syncthreads();
    }
    if (t < 128) {
        int loff = incl[t] - deg[t];          // exclusive local offset
        cur[t] = b0 + loff;                   // global write cursor
        int n = (s << SSHIFT) + t;
        if (n < N) {
            row_ptr[n] = b0 + loff;
            dinv[n] = rsqrtf((float)(deg[t] + 1));   // +1 self loop
        }
    }
    if (s == NS - 1 && t == 0) row_ptr[N] = E;
    __syncthreads();
    for (int k = t; k < cnt; k += 256) {
        int v = eb[b0 + k];
        int dl = v >> 17;
        int p = atomicAdd(&cur[dl], 1);
        csr_src[p] = v & 0x1FFFF;
    }
}

// ---------------------------------------------------------------------------
// GEMM1: h1 = (x @ W1) * dinv[n]   [N,128] @ [128,64], dinv folded in epilogue
// ---------------------------------------------------------------------------
__global__ __launch_bounds__(256) void gemm1_kernel(const float* __restrict__ x,
                                                    const float* __restrict__ W1,
                                                    const float* __restrict__ dinv,
                                                    float* __restrict__ h1, int N) {
    __shared__ __align__(16) float sW[IN_DIM * HID_DIM];   // 32 KB
    __shared__ __align__(16) float sx[16 * IN_DIM];        // 8 KB
    int t = threadIdx.x;
    int node0 = blockIdx.x * 16;

    const float4* W4  = (const float4*)W1;
    float4*       sW4 = (float4*)sW;
    for (int i = t; i < (IN_DIM * HID_DIM) / 4; i += 256) sW4[i] = W4[i];

    const float4* x4  = (const float4*)x;
    float4*       sx4 = (float4*)sx;
    for (int i = t; i < (16 * IN_DIM) / 4; i += 256) {
        int r = i >> 5, c = i & 31;
        int n = node0 + r; if (n >= N) n = 0;
        sx4[(r << 5) + c] = x4[(size_t)n * 32 + c];
    }
    __syncthreads();

    int ln = t >> 4, jj = t & 15;
    int n = node0 + ln;
    float4 acc = {0.f, 0.f, 0.f, 0.f};
    const float* xr = sx + ln * IN_DIM;
    #pragma unroll 4
    for (int k = 0; k < IN_DIM; ++k) {
        float  xk = xr[k];
        float4 wv = ((const float4*)(sW + k * HID_DIM))[jj];
        acc.x += xk * wv.x; acc.y += xk * wv.y; acc.z += xk * wv.z; acc.w += xk * wv.w;
    }
    if (n < N) {
        float dn = dinv[n];
        acc.x *= dn; acc.y *= dn; acc.z *= dn; acc.w *= dn;
        ((float4*)(h1 + (size_t)n * HID_DIM))[jj] = acc;
    }
}

// ---------------------------------------------------------------------------
// Aggregation layer 1: one wave per node; h1 pre-scaled by dinv[src].
// out = relu( dinv[n] * ( h1[n] + sum h1[src] ) + b1 )
// ---------------------------------------------------------------------------
__global__ __launch_bounds__(256) void agg1_kernel(const float* __restrict__ h1,
                                                   const int* __restrict__ row_ptr,
                                                   const int* __restrict__ csr_src,
                                                   const float* __restrict__ dinv,
                                                   const float* __restrict__ b1,
                                                   float* __restrict__ h1a, int N) {
    int t = threadIdx.x;
    int n = blockIdx.x * 4 + (t >> 6);
    int d = t & 63;
    if (n >= N) return;
    float acc0 = h1[(size_t)n * HID_DIM + d];   // self loop (pre-scaled)
    float acc1 = 0.f, acc2 = 0.f, acc3 = 0.f;
    int e0 = row_ptr[n], e1 = row_ptr[n + 1];
    int e = e0;
    for (; e + 3 < e1; e += 4) {
        int s0 = csr_src[e], s1 = csr_src[e + 1], s2 = csr_src[e + 2], s3 = csr_src[e + 3];
        acc0 += h1[(size_t)s0 * HID_DIM + d];
        acc1 += h1[(size_t)s1 * HID_DIM + d];
        acc2 += h1[(size_t)s2 * HID_DIM + d];
        acc3 += h1[(size_t)s3 * HID_DIM + d];
    }
    for (; e < e1; ++e) acc1 += h1[(size_t)csr_src[e] * HID_DIM + d];
    float acc = (acc0 + acc1) + (acc2 + acc3);
    h1a[(size_t)n * HID_DIM + d] = fmaxf(dinv[n] * acc + b1[d], 0.0f);
}

// ---------------------------------------------------------------------------
// GEMM2: h2 = (h1a @ W2) * dinv[n]   [N,64] @ [64,16]
// ---------------------------------------------------------------------------
__global__ __launch_bounds__(256) void gemm2_kernel(const float* __restrict__ h1a,
                                                    const float* __restrict__ W2,
                                                    const float* __restrict__ dinv,
                                                    float* __restrict__ h2, int N) {
    __shared__ __align__(16) float sW[HID_DIM * OUT_DIM];  // 4 KB
    __shared__ __align__(16) float sx[16 * HID_DIM];       // 4 KB
    int t = threadIdx.x;
    int node0 = blockIdx.x * 16;

    ((float4*)sW)[t] = ((const float4*)W2)[t];
    {
        int r = t >> 4, c = t & 15;
        int n = node0 + r; if (n >= N) n = 0;
        ((float4*)sx)[(r << 4) + c] = ((const float4*)h1a)[(size_t)n * 16 + c];
    }
    __syncthreads();

    int ln = t >> 4, j = t & 15;
    float acc = 0.f;
    const float* xr = sx + ln * HID_DIM;
    #pragma unroll 8
    for (int k = 0; k < HID_DIM; ++k) acc += xr[k] * sW[k * OUT_DIM + j];
    int n = node0 + ln;
    if (n < N) h2[(size_t)n * OUT_DIM + j] = acc * dinv[n];
}

// ---------------------------------------------------------------------------
// Aggregation layer 2: 16 lanes per node; h2 pre-scaled by dinv[src].
// out = dinv[n]*(h2[n] + sum h2[src]) + b2
// ---------------------------------------------------------------------------
__global__ __launch_bounds__(256) void agg2_kernel(const float* __restrict__ h2,
                                                   const int* __restrict__ row_ptr,
                                                   const int* __restrict__ csr_src,
                                                   const float* __restrict__ dinv,
                                                   const float* __restrict__ b2,
                                                   float* __restrict__ out, int N) {
    int t = threadIdx.x;
    int n = blockIdx.x * 16 + (t >> 4);
    int d = t & 15;
    if (n >= N) return;
    float acc0 = h2[(size_t)n * OUT_DIM + d];
    float acc1 = 0.f, acc2 = 0.f, acc3 = 0.f;
    int e0 = row_ptr[n], e1 = row_ptr[n + 1];
    int e = e0;
    for (; e + 3 < e1; e += 4) {
        int s0 = csr_src[e], s1 = csr_src[e + 1], s2 = csr_src[e + 2], s3 = csr_src[e + 3];
        acc0 += h2[(size_t)s0 * OUT_DIM + d];
        acc1 += h2[(size_t)s1 * OUT_DIM + d];
        acc2 += h2[(size_t)s2 * OUT_DIM + d];
        acc3 += h2[(size_t)s3 * OUT_DIM + d];
    }
    for (; e < e1; ++e) acc1 += h2[(size_t)csr_src[e] * OUT_DIM + d];
    float acc = (acc0 + acc1) + (acc2 + acc3);
    out[(size_t)n * OUT_DIM + d] = dinv[n] * acc + b2[d];
}

// ---------------------------------------------------------------------------
// Launch
// ---------------------------------------------------------------------------
extern "C" void kernel_launch(void* const* d_in, const int* in_sizes, int n_in,
                              void* d_out, int out_size, void* d_ws, size_t ws_size,
                              hipStream_t stream) {
    const float* x  = (const float*)d_in[0];
    const int*   ei = (const int*)d_in[1];
    const float* W1 = (const float*)d_in[2];
    const float* b1 = (const float*)d_in[3];
    const float* W2 = (const float*)d_in[4];
    const float* b2 = (const float*)d_in[5];
    float* out = (float*)d_out;

    const int N = in_sizes[0] / IN_DIM;   // 50000
    const int E = in_sizes[1] / 2;        // 1000000
    const int* src = ei;
    const int* dst = ei + E;

    const int NS  = (N + SMASK) >> SSHIFT;       // 391 stripes
    const int NSP = NS + 1;                      // padded stride
    const int BC  = (E + CHUNK - 1) / CHUNK;     // 62 chunks (must be <= 64)

    // Workspace layout (256 B aligned slices)
    char* w = (char*)d_ws;
    auto alloc = [&](size_t bytes) -> void* {
        void* p = (void*)w;
        w += (bytes + 255) & ~(size_t)255;
        return p;
    };
    int*   cm      = (int*)  alloc((size_t)BC * NSP * 4);
    int*   tot     = (int*)  alloc((size_t)NS * 4);
    int*   sbase   = (int*)  alloc((size_t)NS * 4);
    int*   eb      = (int*)  alloc((size_t)E * 4);
    int*   csr_src = (int*)  alloc((size_t)E * 4);
    int*   row_ptr = (int*)  alloc((size_t)(N + 1) * 4);
    float* dinv    = (float*)alloc((size_t)N * 4);
    float* h1      = (float*)alloc((size_t)N * HID_DIM * 4);
    float* h1a     = (float*)alloc((size_t)N * HID_DIM * 4);
    float* h2      = (float*)alloc((size_t)N * OUT_DIM * 4);

    const int GB = (N + 15) / 16;

    passA <<<BC, CBLK, 0, stream>>>(dst, cm, E, NS, NSP);
    passB1<<<NS, 64,   0, stream>>>(cm, tot, BC, NSP);
    passB2<<<1,  512,  0, stream>>>(tot, sbase, NS);
    passC <<<BC, CBLK, 0, stream>>>(src, dst, cm, sbase, eb, E, NS, NSP);
    passD <<<NS, 256,  0, stream>>>(eb, sbase, tot, csr_src, row_ptr, dinv, N, E, NS);

    gemm1_kernel<<<GB, 256, 0, stream>>>(x, W1, dinv, h1, N);
    agg1_kernel<<<(N + 3) / 4, 256, 0, stream>>>(h1, row_ptr, csr_src, dinv, b1, h1a, N);
    gemm2_kernel<<<GB, 256, 0, stream>>>(h1a, W2, dinv, h2, N);
    agg2_kernel<<<GB, 256, 0, stream>>>(h2, row_ptr, csr_src, dinv, b2, out, N);
}

// Round 4
// 190.152 us; speedup vs baseline: 1.4953x; 1.0875x over previous
//
#include <hip/hip_runtime.h>
#include <hip/hip_bf16.h>

#define IN_DIM 128
#define HID_DIM 64
#define OUT_DIM 16

// Stripe/bin geometry: 128 nodes per stripe
#define SSHIFT 7
#define SMASK 127
// Edge chunking for passes A/C
#define CHUNK 16384
#define CBLK 1024

// bf16 helpers: round-to-nearest-even pack, bit-shift unpack
static __device__ __forceinline__ unsigned short f2bf(float f) {
    unsigned u = __float_as_uint(f);
    unsigned r = u + 0x7fffu + ((u >> 16) & 1u);
    return (unsigned short)(r >> 16);
}
static __device__ __forceinline__ unsigned packbf2(float a, float b) {
    return (unsigned)f2bf(a) | ((unsigned)f2bf(b) << 16);
}
static __device__ __forceinline__ float bflo(unsigned v) { return __uint_as_float(v << 16); }
static __device__ __forceinline__ float bfhi(unsigned v) { return __uint_as_float(v & 0xffff0000u); }

// ---------------------------------------------------------------------------
// passA: per-block per-stripe histogram (LDS only, no global atomics)
// ---------------------------------------------------------------------------
__global__ __launch_bounds__(CBLK) void passA(const int* __restrict__ dst,
                                              int* __restrict__ cm,
                                              int E, int NS, int NSP) {
    __shared__ int cnt[512];
    int t = threadIdx.x;
    for (int s = t; s < NS; s += CBLK) cnt[s] = 0;
    __syncthreads();
    int base = blockIdx.x * CHUNK;
    #pragma unroll 4
    for (int k = 0; k < CHUNK; k += CBLK) {
        int i = base + k + t;
        if (i < E) atomicAdd(&cnt[dst[i] >> SSHIFT], 1);
    }
    __syncthreads();
    for (int s = t; s < NS; s += CBLK) cm[blockIdx.x * NSP + s] = cnt[s];
}

// ---------------------------------------------------------------------------
// passB1: per-stripe exclusive scan over blocks; tot[s] = sum. B <= 64.
// ---------------------------------------------------------------------------
__global__ __launch_bounds__(64) void passB1(int* __restrict__ cm, int* __restrict__ tot,
                                             int B, int NSP) {
    __shared__ int sv[64];
    int t = threadIdx.x, s = blockIdx.x;
    int v = (t < B) ? cm[t * NSP + s] : 0;
    sv[t] = v;
    __syncthreads();
    for (int off = 1; off < 64; off <<= 1) {
        int tmp = (t >= off) ? sv[t - off] : 0;
        __syncthreads();
        sv[t] += tmp;
        __syncthreads();
    }
    if (t < B) cm[t * NSP + s] = sv[t] - v;
    if (t == 63) tot[s] = sv[63];
}

// ---------------------------------------------------------------------------
// passB2: exclusive scan of stripe totals -> stripe base offsets (NS <= 512)
// ---------------------------------------------------------------------------
__global__ __launch_bounds__(512) void passB2(const int* __restrict__ tot,
                                              int* __restrict__ sbase, int NS) {
    __shared__ int sv[512];
    int t = threadIdx.x;
    int v = (t < NS) ? tot[t] : 0;
    sv[t] = v;
    __syncthreads();
    for (int off = 1; off < 512; off <<= 1) {
        int tmp = (t >= off) ? sv[t - off] : 0;
        __syncthreads();
        sv[t] += tmp;
        __syncthreads();
    }
    if (t < NS) sbase[t] = sv[t] - v;
}

// ---------------------------------------------------------------------------
// passC: bucket edges by stripe; LDS cursors; packed (dl<<17)|src
// ---------------------------------------------------------------------------
__global__ __launch_bounds__(CBLK) void passC(const int* __restrict__ src,
                                              const int* __restrict__ dst,
                                              const int* __restrict__ cm,
                                              const int* __restrict__ sbase,
                                              int* __restrict__ eb,
                                              int E, int NS, int NSP) {
    __shared__ int cur[512];
    int t = threadIdx.x, b = blockIdx.x;
    for (int s = t; s < NS; s += CBLK) cur[s] = sbase[s] + cm[b * NSP + s];
    __syncthreads();
    int base = b * CHUNK;
    #pragma unroll 4
    for (int k = 0; k < CHUNK; k += CBLK) {
        int i = base + k + t;
        if (i < E) {
            int d = dst[i];
            int s = d >> SSHIFT;
            int pos = atomicAdd(&cur[s], 1);
            eb[pos] = src[i] | ((d & SMASK) << 17);
        }
    }
}

// ---------------------------------------------------------------------------
// passD: per-stripe LDS counting sort -> exact CSR + row_ptr + dinv.
// ---------------------------------------------------------------------------
__global__ __launch_bounds__(256) void passD(const int* __restrict__ eb,
                                             const int* __restrict__ sbase,
                                             const int* __restrict__ tot,
                                             int* __restrict__ csr_src,
                                             int* __restrict__ row_ptr,
                                             float* __restrict__ dinv,
                                             int N, int E, int NS) {
    __shared__ int deg[128], incl[128], cur[128];
    int s = blockIdx.x, t = threadIdx.x;
    if (t < 128) deg[t] = 0;
    __syncthreads();
    int b0 = sbase[s], cnt = tot[s];
    for (int k = t; k < cnt; k += 256) atomicAdd(&deg[eb[b0 + k] >> 17], 1);
    __syncthreads();
    if (t < 128) incl[t] = deg[t];
    __syncthreads();
    for (int off = 1; off < 128; off <<= 1) {
        int tmp = 0;
        if (t < 128 && t >= off) tmp = incl[t - off];
        __syncthreads();
        if (t < 128) incl[t] += tmp;
        __syncthreads();
    }
    if (t < 128) {
        int loff = incl[t] - deg[t];
        cur[t] = b0 + loff;
        int n = (s << SSHIFT) + t;
        if (n < N) {
            row_ptr[n] = b0 + loff;
            dinv[n] = rsqrtf((float)(deg[t] + 1));
        }
    }
    if (s == NS - 1 && t == 0) row_ptr[N] = E;
    __syncthreads();
    for (int k = t; k < cnt; k += 256) {
        int v = eb[b0 + k];
        int dl = v >> 17;
        int p = atomicAdd(&cur[dl], 1);
        csr_src[p] = v & 0x1FFFF;
    }
}

// ---------------------------------------------------------------------------
// GEMM1: h1 = bf16( (x @ W1) * dinv[n] ), row = 32 uints. Row N = zeros (dummy).
// ---------------------------------------------------------------------------
__global__ __launch_bounds__(256) void gemm1_kernel(const float* __restrict__ x,
                                                    const float* __restrict__ W1,
                                                    const float* __restrict__ dinv,
                                                    unsigned* __restrict__ h1u, int N) {
    __shared__ __align__(16) float sW[IN_DIM * HID_DIM];   // 32 KB
    __shared__ __align__(16) float sx[16 * IN_DIM];        // 8 KB
    int t = threadIdx.x;
    int node0 = blockIdx.x * 16;

    const float4* W4  = (const float4*)W1;
    float4*       sW4 = (float4*)sW;
    for (int i = t; i < (IN_DIM * HID_DIM) / 4; i += 256) sW4[i] = W4[i];

    const float4* x4  = (const float4*)x;
    float4*       sx4 = (float4*)sx;
    for (int i = t; i < (16 * IN_DIM) / 4; i += 256) {
        int r = i >> 5, c = i & 31;
        int n = node0 + r; if (n >= N) n = 0;   // clamp; dummy row gets dn=0
        sx4[(r << 5) + c] = x4[(size_t)n * 32 + c];
    }
    __syncthreads();

    int ln = t >> 4, jj = t & 15;
    int n = node0 + ln;
    float4 acc = {0.f, 0.f, 0.f, 0.f};
    const float* xr = sx + ln * IN_DIM;
    #pragma unroll 4
    for (int k = 0; k < IN_DIM; ++k) {
        float  xk = xr[k];
        float4 wv = ((const float4*)(sW + k * HID_DIM))[jj];
        acc.x += xk * wv.x; acc.y += xk * wv.y; acc.z += xk * wv.z; acc.w += xk * wv.w;
    }
    if (n <= N) {
        float dn = (n < N) ? dinv[n] : 0.f;     // row N -> zeros
        uint2 pv;
        pv.x = packbf2(acc.x * dn, acc.y * dn);
        pv.y = packbf2(acc.z * dn, acc.w * dn);
        ((uint2*)(h1u + (size_t)n * 32))[jj] = pv;
    }
}

// ---------------------------------------------------------------------------
// Aggregation layer 1: one wave per node; 2 edges per load instruction
// (half-wave = one edge, 32 lanes x uint = 64 bf16 dims). h1 pre-scaled by
// dinv[src]. out = relu( dinv[n]*(h1[n] + sum h1[src]) + b1 ), bf16.
// ---------------------------------------------------------------------------
__global__ __launch_bounds__(256) void agg1_kernel(const unsigned* __restrict__ h1u,
                                                   const int* __restrict__ row_ptr,
                                                   const int* __restrict__ csr_src,
                                                   const float* __restrict__ dinv,
                                                   const float* __restrict__ b1,
                                                   unsigned* __restrict__ h1au, int N) {
    int t = threadIdx.x;
    int n = blockIdx.x * 4 + (t >> 6);
    if (n >= N) return;
    int lane = t & 63;
    int half = lane >> 5;      // which edge of the pair
    int l    = lane & 31;      // dim pair (dims 2l, 2l+1)

    int srow = half ? N : n;   // self loop in half 0; zero row in half 1
    unsigned v = h1u[(size_t)srow * 32 + l];
    float ax = bflo(v), ay = bfhi(v);

    int e1 = row_ptr[n + 1];
    int e  = row_ptr[n];
    for (; e + 8 <= e1; e += 8) {
        int s0 = csr_src[e + 0 + half];
        int s1 = csr_src[e + 2 + half];
        int s2 = csr_src[e + 4 + half];
        int s3 = csr_src[e + 6 + half];
        unsigned v0 = h1u[(size_t)s0 * 32 + l];
        unsigned v1 = h1u[(size_t)s1 * 32 + l];
        unsigned v2 = h1u[(size_t)s2 * 32 + l];
        unsigned v3 = h1u[(size_t)s3 * 32 + l];
        ax += bflo(v0) + bflo(v1) + bflo(v2) + bflo(v3);
        ay += bfhi(v0) + bfhi(v1) + bfhi(v2) + bfhi(v3);
    }
    for (; e < e1; e += 2) {
        int idx = e + half;
        int s = (idx < e1) ? csr_src[idx] : N;   // odd tail -> zero row
        unsigned vv = h1u[(size_t)s * 32 + l];
        ax += bflo(vv);
        ay += bfhi(vv);
    }
    ax += __shfl_xor(ax, 32);
    ay += __shfl_xor(ay, 32);
    if (half == 0) {
        float dn = dinv[n];
        float2 bb = ((const float2*)b1)[l];
        float r0 = fmaxf(fmaf(dn, ax, bb.x), 0.f);
        float r1 = fmaxf(fmaf(dn, ay, bb.y), 0.f);
        h1au[(size_t)n * 32 + l] = packbf2(r0, r1);
    }
}

// ---------------------------------------------------------------------------
// GEMM2: h2 = bf16( (h1a @ W2) * dinv[n] ), row = 8 uints. Row N = zeros.
// ---------------------------------------------------------------------------
__global__ __launch_bounds__(256) void gemm2_kernel(const unsigned* __restrict__ h1au,
                                                    const float* __restrict__ W2,
                                                    const float* __restrict__ dinv,
                                                    unsigned* __restrict__ h2u, int N) {
    __shared__ __align__(16) float sW[HID_DIM * OUT_DIM];  // 4 KB
    __shared__ __align__(16) float sx[16 * HID_DIM];       // 4 KB
    int t = threadIdx.x;
    int node0 = blockIdx.x * 16;

    ((float4*)sW)[t] = ((const float4*)W2)[t];
    for (int i = t; i < 512; i += 256) {           // 16 rows x 32 uints
        int r = i >> 5, c = i & 31;
        int n = node0 + r; if (n >= N) n = 0;      // clamp; dummy handled by dn=0
        unsigned v = h1au[(size_t)n * 32 + c];
        float2 f; f.x = bflo(v); f.y = bfhi(v);
        *(float2*)(sx + r * HID_DIM + 2 * c) = f;
    }
    __syncthreads();

    int ln = t >> 4, j = t & 15;
    float acc = 0.f;
    const float* xr = sx + ln * HID_DIM;
    #pragma unroll 8
    for (int k = 0; k < HID_DIM; ++k) acc += xr[k] * sW[k * OUT_DIM + j];
    int n = node0 + ln;
    float other = __shfl_xor(acc, 1);              // pair dims (j even, j odd)
    if (n <= N && (j & 1) == 0) {
        float dn = (n < N) ? dinv[n] : 0.f;        // row N -> zeros
        h2u[(size_t)n * 8 + (j >> 1)] = packbf2(acc * dn, other * dn);
    }
}

// ---------------------------------------------------------------------------
// Aggregation layer 2: 16 lanes/node (2 halves x 8 dim-pairs); 2 edges per
// load instruction. h2 pre-scaled by dinv[src]. out = dinv[n]*sum + b2, fp32.
// ---------------------------------------------------------------------------
__global__ __launch_bounds__(256) void agg2_kernel(const unsigned* __restrict__ h2u,
                                                   const int* __restrict__ row_ptr,
                                                   const int* __restrict__ csr_src,
                                                   const float* __restrict__ dinv,
                                                   const float* __restrict__ b2,
                                                   float* __restrict__ out, int N) {
    int t = threadIdx.x;
    int n = blockIdx.x * 16 + (t >> 4);
    if (n >= N) return;
    int half = (t >> 3) & 1;
    int l    = t & 7;          // dims 2l, 2l+1

    int srow = half ? N : n;
    unsigned v = h2u[(size_t)srow * 8 + l];
    float ax = bflo(v), ay = bfhi(v);

    int e1 = row_ptr[n + 1];
    int e  = row_ptr[n];
    for (; e + 8 <= e1; e += 8) {
        int s0 = csr_src[e + 0 + half];
        int s1 = csr_src[e + 2 + half];
        int s2 = csr_src[e + 4 + half];
        int s3 = csr_src[e + 6 + half];
        unsigned v0 = h2u[(size_t)s0 * 8 + l];
        unsigned v1 = h2u[(size_t)s1 * 8 + l];
        unsigned v2 = h2u[(size_t)s2 * 8 + l];
        unsigned v3 = h2u[(size_t)s3 * 8 + l];
        ax += bflo(v0) + bflo(v1) + bflo(v2) + bflo(v3);
        ay += bfhi(v0) + bfhi(v1) + bfhi(v2) + bfhi(v3);
    }
    for (; e < e1; e += 2) {
        int idx = e + half;
        int s = (idx < e1) ? csr_src[idx] : N;
        unsigned vv = h2u[(size_t)s * 8 + l];
        ax += bflo(vv);
        ay += bfhi(vv);
    }
    ax += __shfl_xor(ax, 8);
    ay += __shfl_xor(ay, 8);
    if (half == 0) {
        float dn = dinv[n];
        float2 bb = ((const float2*)b2)[l];
        float2 r;
        r.x = fmaf(dn, ax, bb.x);
        r.y = fmaf(dn, ay, bb.y);
        ((float2*)out)[(size_t)n * 8 + l] = r;
    }
}

// ---------------------------------------------------------------------------
// Launch
// ---------------------------------------------------------------------------
extern "C" void kernel_launch(void* const* d_in, const int* in_sizes, int n_in,
                              void* d_out, int out_size, void* d_ws, size_t ws_size,
                              hipStream_t stream) {
    const float* x  = (const float*)d_in[0];
    const int*   ei = (const int*)d_in[1];
    const float* W1 = (const float*)d_in[2];
    const float* b1 = (const float*)d_in[3];
    const float* W2 = (const float*)d_in[4];
    const float* b2 = (const float*)d_in[5];
    float* out = (float*)d_out;

    const int N = in_sizes[0] / IN_DIM;   // 50000
    const int E = in_sizes[1] / 2;        // 1000000
    const int* src = ei;
    const int* dst = ei + E;

    const int NS  = (N + SMASK) >> SSHIFT;       // 391 stripes
    const int NSP = NS + 1;
    const int BC  = (E + CHUNK - 1) / CHUNK;     // 62 chunks (<= 64)

    char* w = (char*)d_ws;
    auto alloc = [&](size_t bytes) -> void* {
        void* p = (void*)w;
        w += (bytes + 255) & ~(size_t)255;
        return p;
    };
    int*      cm      = (int*)     alloc((size_t)BC * NSP * 4);
    int*      tot     = (int*)     alloc((size_t)NS * 4);
    int*      sbase   = (int*)     alloc((size_t)NS * 4);
    int*      eb      = (int*)     alloc((size_t)E * 4);
    int*      csr_src = (int*)     alloc((size_t)E * 4);
    int*      row_ptr = (int*)     alloc((size_t)(N + 1) * 4);
    float*    dinv    = (float*)   alloc((size_t)N * 4);
    unsigned* h1u     = (unsigned*)alloc((size_t)(N + 1) * 32 * 4);  // bf16 [N+1][64]
    unsigned* h1au    = (unsigned*)alloc((size_t)(N + 1) * 32 * 4);
    unsigned* h2u     = (unsigned*)alloc((size_t)(N + 1) * 8 * 4);   // bf16 [N+1][16]

    const int GB = (N + 16) / 16;    // covers rows 0..N (incl. dummy)

    passA <<<BC, CBLK, 0, stream>>>(dst, cm, E, NS, NSP);
    passB1<<<NS, 64,   0, stream>>>(cm, tot, BC, NSP);
    passB2<<<1,  512,  0, stream>>>(tot, sbase, NS);
    passC <<<BC, CBLK, 0, stream>>>(src, dst, cm, sbase, eb, E, NS, NSP);
    passD <<<NS, 256,  0, stream>>>(eb, sbase, tot, csr_src, row_ptr, dinv, N, E, NS);

    gemm1_kernel<<<GB, 256, 0, stream>>>(x, W1, dinv, h1u, N);
    agg1_kernel<<<(N + 3) / 4, 256, 0, stream>>>(h1u, row_ptr, csr_src, dinv, b1, h1au, N);
    gemm2_kernel<<<GB, 256, 0, stream>>>(h1au, W2, dinv, h2u, N);
    agg2_kernel<<<GB, 256, 0, stream>>>(h2u, row_ptr, csr_src, dinv, b2, out, N);
}

// Round 5
// 187.448 us; speedup vs baseline: 1.5169x; 1.0144x over previous
//
#include <hip/hip_runtime.h>
#include <hip/hip_bf16.h>

#define IN_DIM 128
#define HID_DIM 64
#define OUT_DIM 16

// Stripe/bin geometry: 128 nodes per stripe
#define SSHIFT 7
#define SMASK 127
// Edge chunking for passes A/C
#define CHUNK 16384
#define CBLK 1024

// bf16 helpers: round-to-nearest-even pack, bit-shift unpack
static __device__ __forceinline__ unsigned short f2bf(float f) {
    unsigned u = __float_as_uint(f);
    unsigned r = u + 0x7fffu + ((u >> 16) & 1u);
    return (unsigned short)(r >> 16);
}
static __device__ __forceinline__ unsigned packbf2(float a, float b) {
    return (unsigned)f2bf(a) | ((unsigned)f2bf(b) << 16);
}
static __device__ __forceinline__ float bflo(unsigned v) { return __uint_as_float(v << 16); }
static __device__ __forceinline__ float bfhi(unsigned v) { return __uint_as_float(v & 0xffff0000u); }

// ---------------------------------------------------------------------------
// passA: per-block per-stripe histogram (LDS only, no global atomics)
// ---------------------------------------------------------------------------
__global__ __launch_bounds__(CBLK) void passA(const int* __restrict__ dst,
                                              int* __restrict__ cm,
                                              int E, int NS, int NSP) {
    __shared__ int cnt[512];
    int t = threadIdx.x;
    for (int s = t; s < NS; s += CBLK) cnt[s] = 0;
    __syncthreads();
    int base = blockIdx.x * CHUNK;
    #pragma unroll 4
    for (int k = 0; k < CHUNK; k += CBLK) {
        int i = base + k + t;
        if (i < E) atomicAdd(&cnt[dst[i] >> SSHIFT], 1);
    }
    __syncthreads();
    for (int s = t; s < NS; s += CBLK) cm[blockIdx.x * NSP + s] = cnt[s];
}

// ---------------------------------------------------------------------------
// passB1: per-stripe exclusive scan over blocks; tot[s] = sum. B <= 64.
// ---------------------------------------------------------------------------
__global__ __launch_bounds__(64) void passB1(int* __restrict__ cm, int* __restrict__ tot,
                                             int B, int NSP) {
    __shared__ int sv[64];
    int t = threadIdx.x, s = blockIdx.x;
    int v = (t < B) ? cm[t * NSP + s] : 0;
    sv[t] = v;
    __syncthreads();
    for (int off = 1; off < 64; off <<= 1) {
        int tmp = (t >= off) ? sv[t - off] : 0;
        __syncthreads();
        sv[t] += tmp;
        __syncthreads();
    }
    if (t < B) cm[t * NSP + s] = sv[t] - v;
    if (t == 63) tot[s] = sv[63];
}

// ---------------------------------------------------------------------------
// passB2: exclusive scan of stripe totals -> stripe base offsets (NS <= 512)
// ---------------------------------------------------------------------------
__global__ __launch_bounds__(512) void passB2(const int* __restrict__ tot,
                                              int* __restrict__ sbase, int NS) {
    __shared__ int sv[512];
    int t = threadIdx.x;
    int v = (t < NS) ? tot[t] : 0;
    sv[t] = v;
    __syncthreads();
    for (int off = 1; off < 512; off <<= 1) {
        int tmp = (t >= off) ? sv[t - off] : 0;
        __syncthreads();
        sv[t] += tmp;
        __syncthreads();
    }
    if (t < NS) sbase[t] = sv[t] - v;
}

// ---------------------------------------------------------------------------
// passC: bucket edges by stripe; LDS cursors; packed (dl<<17)|src
// ---------------------------------------------------------------------------
__global__ __launch_bounds__(CBLK) void passC(const int* __restrict__ src,
                                              const int* __restrict__ dst,
                                              const int* __restrict__ cm,
                                              const int* __restrict__ sbase,
                                              int* __restrict__ eb,
                                              int E, int NS, int NSP) {
    __shared__ int cur[512];
    int t = threadIdx.x, b = blockIdx.x;
    for (int s = t; s < NS; s += CBLK) cur[s] = sbase[s] + cm[b * NSP + s];
    __syncthreads();
    int base = b * CHUNK;
    #pragma unroll 4
    for (int k = 0; k < CHUNK; k += CBLK) {
        int i = base + k + t;
        if (i < E) {
            int d = dst[i];
            int s = d >> SSHIFT;
            int pos = atomicAdd(&cur[s], 1);
            eb[pos] = src[i] | ((d & SMASK) << 17);
        }
    }
}

// ---------------------------------------------------------------------------
// passD: per-stripe LDS counting sort -> exact CSR + row_ptr + dinv.
// ---------------------------------------------------------------------------
__global__ __launch_bounds__(256) void passD(const int* __restrict__ eb,
                                             const int* __restrict__ sbase,
                                             const int* __restrict__ tot,
                                             int* __restrict__ csr_src,
                                             int* __restrict__ row_ptr,
                                             float* __restrict__ dinv,
                                             int N, int E, int NS) {
    __shared__ int deg[128], incl[128], cur[128];
    int s = blockIdx.x, t = threadIdx.x;
    if (t < 128) deg[t] = 0;
    __syncthreads();
    int b0 = sbase[s], cnt = tot[s];
    for (int k = t; k < cnt; k += 256) atomicAdd(&deg[eb[b0 + k] >> 17], 1);
    __syncthreads();
    if (t < 128) incl[t] = deg[t];
    __syncthreads();
    for (int off = 1; off < 128; off <<= 1) {
        int tmp = 0;
        if (t < 128 && t >= off) tmp = incl[t - off];
        __syncthreads();
        if (t < 128) incl[t] += tmp;
        __syncthreads();
    }
    if (t < 128) {
        int loff = incl[t] - deg[t];
        cur[t] = b0 + loff;
        int n = (s << SSHIFT) + t;
        if (n < N) {
            row_ptr[n] = b0 + loff;
            dinv[n] = rsqrtf((float)(deg[t] + 1));
        }
    }
    if (s == NS - 1 && t == 0) row_ptr[N] = E;
    __syncthreads();
    for (int k = t; k < cnt; k += 256) {
        int v = eb[b0 + k];
        int dl = v >> 17;
        int p = atomicAdd(&cur[dl], 1);
        csr_src[p] = v & 0x1FFFF;
    }
}

// ---------------------------------------------------------------------------
// GEMM1: h1 = bf16( (x @ W1) * dinv[n] ), row = 32 uints. Row N = zeros (dummy).
// ---------------------------------------------------------------------------
__global__ __launch_bounds__(256) void gemm1_kernel(const float* __restrict__ x,
                                                    const float* __restrict__ W1,
                                                    const float* __restrict__ dinv,
                                                    unsigned* __restrict__ h1u, int N) {
    __shared__ __align__(16) float sW[IN_DIM * HID_DIM];   // 32 KB
    __shared__ __align__(16) float sx[16 * IN_DIM];        // 8 KB
    int t = threadIdx.x;
    int node0 = blockIdx.x * 16;

    const float4* W4  = (const float4*)W1;
    float4*       sW4 = (float4*)sW;
    for (int i = t; i < (IN_DIM * HID_DIM) / 4; i += 256) sW4[i] = W4[i];

    const float4* x4  = (const float4*)x;
    float4*       sx4 = (float4*)sx;
    for (int i = t; i < (16 * IN_DIM) / 4; i += 256) {
        int r = i >> 5, c = i & 31;
        int n = node0 + r; if (n >= N) n = 0;   // clamp; dummy row gets dn=0
        sx4[(r << 5) + c] = x4[(size_t)n * 32 + c];
    }
    __syncthreads();

    int ln = t >> 4, jj = t & 15;
    int n = node0 + ln;
    float4 acc = {0.f, 0.f, 0.f, 0.f};
    const float* xr = sx + ln * IN_DIM;
    #pragma unroll 4
    for (int k = 0; k < IN_DIM; ++k) {
        float  xk = xr[k];
        float4 wv = ((const float4*)(sW + k * HID_DIM))[jj];
        acc.x += xk * wv.x; acc.y += xk * wv.y; acc.z += xk * wv.z; acc.w += xk * wv.w;
    }
    if (n <= N) {
        float dn = (n < N) ? dinv[n] : 0.f;     // row N -> zeros
        uint2 pv;
        pv.x = packbf2(acc.x * dn, acc.y * dn);
        pv.y = packbf2(acc.z * dn, acc.w * dn);
        ((uint2*)(h1u + (size_t)n * 32))[jj] = pv;
    }
}

// ---------------------------------------------------------------------------
// Aggregation layer 1 (v3): one wave per node. lane = (es 0..7, dg 0..7).
// Each lane loads uint4 = 8 bf16 dims -> ONE dwordx4 instruction fetches
// 8 full edge rows (1 KB). Edge indices for 64 items prefetched with one
// coalesced load, redistributed by __shfl. Self-loop = item e0-1; slots
// past e1 clamp to zero dummy row N. 2 rounds unrolled (16 rows in flight).
// out = relu( dinv[n]*(h1[n] + sum h1[src]) + b1 ), bf16.
// ---------------------------------------------------------------------------
__global__ __launch_bounds__(256) void agg1_kernel(const unsigned* __restrict__ h1u,
                                                   const int* __restrict__ row_ptr,
                                                   const int* __restrict__ csr_src,
                                                   const float* __restrict__ dinv,
                                                   const float* __restrict__ b1,
                                                   unsigned* __restrict__ h1au, int N) {
    int t = threadIdx.x;
    int n = blockIdx.x * 4 + (t >> 6);
    if (n >= N) return;
    int lane = t & 63;
    int es = lane >> 3;        // edge slot 0..7
    int dg = lane & 7;         // dim group: uint4 = dims 8dg..8dg+7

    int e0 = row_ptr[n], e1 = row_ptr[n + 1];
    const uint4* rb = (const uint4*)h1u;     // row = 8 uint4

    float a0 = 0.f, a1 = 0.f, a2 = 0.f, a3 = 0.f,
          a4 = 0.f, a5 = 0.f, a6 = 0.f, a7 = 0.f;

    for (int base = e0 - 1; base < e1; base += 64) {
        int idx = base + lane;
        int sld = N;
        if (idx == e0 - 1) sld = n;              // self loop item
        else if (idx < e1) sld = csr_src[idx];   // predicated coalesced load
        int lim = e1 - base;                     // valid items this chunk (>=1)
        int nr = (lim + 7) >> 3;                 // rounds of 8
        nr = (nr + 1) & ~1;                      // even # rounds (extras hit row N)
        for (int r = 0; r < nr; r += 2) {
            int sA = __shfl(sld, (r << 3) + es);
            int sB = __shfl(sld, ((r + 1) << 3) + es);
            uint4 vA = rb[(size_t)sA * 8 + dg];
            uint4 vB = rb[(size_t)sB * 8 + dg];
            a0 += bflo(vA.x) + bflo(vB.x);
            a1 += bfhi(vA.x) + bfhi(vB.x);
            a2 += bflo(vA.y) + bflo(vB.y);
            a3 += bfhi(vA.y) + bfhi(vB.y);
            a4 += bflo(vA.z) + bflo(vB.z);
            a5 += bfhi(vA.z) + bfhi(vB.z);
            a6 += bflo(vA.w) + bflo(vB.w);
            a7 += bfhi(vA.w) + bfhi(vB.w);
        }
    }
    // reduce over edge slots (es stride 8 -> xor 8,16,32)
    #pragma unroll
    for (int m = 8; m <= 32; m <<= 1) {
        a0 += __shfl_xor(a0, m); a1 += __shfl_xor(a1, m);
        a2 += __shfl_xor(a2, m); a3 += __shfl_xor(a3, m);
        a4 += __shfl_xor(a4, m); a5 += __shfl_xor(a5, m);
        a6 += __shfl_xor(a6, m); a7 += __shfl_xor(a7, m);
    }
    if (es == 0) {
        float dn = dinv[n];
        float4 bA = ((const float4*)b1)[2 * dg];
        float4 bB = ((const float4*)b1)[2 * dg + 1];
        float r0 = fmaxf(fmaf(dn, a0, bA.x), 0.f);
        float r1 = fmaxf(fmaf(dn, a1, bA.y), 0.f);
        float r2 = fmaxf(fmaf(dn, a2, bA.z), 0.f);
        float r3 = fmaxf(fmaf(dn, a3, bA.w), 0.f);
        float r4 = fmaxf(fmaf(dn, a4, bB.x), 0.f);
        float r5 = fmaxf(fmaf(dn, a5, bB.y), 0.f);
        float r6 = fmaxf(fmaf(dn, a6, bB.z), 0.f);
        float r7 = fmaxf(fmaf(dn, a7, bB.w), 0.f);
        uint4 pv;
        pv.x = packbf2(r0, r1); pv.y = packbf2(r2, r3);
        pv.z = packbf2(r4, r5); pv.w = packbf2(r6, r7);
        ((uint4*)h1au)[(size_t)n * 8 + dg] = pv;
    }
}

// ---------------------------------------------------------------------------
// GEMM2: h2 = bf16( (h1a @ W2) * dinv[n] ), row = 8 uints. Row N = zeros.
// ---------------------------------------------------------------------------
__global__ __launch_bounds__(256) void gemm2_kernel(const unsigned* __restrict__ h1au,
                                                    const float* __restrict__ W2,
                                                    const float* __restrict__ dinv,
                                                    unsigned* __restrict__ h2u, int N) {
    __shared__ __align__(16) float sW[HID_DIM * OUT_DIM];  // 4 KB
    __shared__ __align__(16) float sx[16 * HID_DIM];       // 4 KB
    int t = threadIdx.x;
    int node0 = blockIdx.x * 16;

    ((float4*)sW)[t] = ((const float4*)W2)[t];
    for (int i = t; i < 512; i += 256) {           // 16 rows x 32 uints
        int r = i >> 5, c = i & 31;
        int n = node0 + r; if (n >= N) n = 0;      // clamp; dummy handled by dn=0
        unsigned v = h1au[(size_t)n * 32 + c];
        float2 f; f.x = bflo(v); f.y = bfhi(v);
        *(float2*)(sx + r * HID_DIM + 2 * c) = f;
    }
    __syncthreads();

    int ln = t >> 4, j = t & 15;
    float acc = 0.f;
    const float* xr = sx + ln * HID_DIM;
    #pragma unroll 8
    for (int k = 0; k < HID_DIM; ++k) acc += xr[k] * sW[k * OUT_DIM + j];
    int n = node0 + ln;
    float other = __shfl_xor(acc, 1);              // pair dims (j even, j odd)
    if (n <= N && (j & 1) == 0) {
        float dn = (n < N) ? dinv[n] : 0.f;        // row N -> zeros
        h2u[(size_t)n * 8 + (j >> 1)] = packbf2(acc * dn, other * dn);
    }
}

// ---------------------------------------------------------------------------
// Aggregation layer 2 (v3): one wave per node. lane = (es 0..15, dg 0..3).
// uint2 per lane (4 bf16 dims) -> one load instruction = 16 edge rows.
// h2u (1.6 MB) is L2-resident. out = dinv[n]*sum + b2, fp32.
// ---------------------------------------------------------------------------
__global__ __launch_bounds__(256) void agg2_kernel(const unsigned* __restrict__ h2u,
                                                   const int* __restrict__ row_ptr,
                                                   const int* __restrict__ csr_src,
                                                   const float* __restrict__ dinv,
                                                   const float* __restrict__ b2,
                                                   float* __restrict__ out, int N) {
    int t = threadIdx.x;
    int n = blockIdx.x * 4 + (t >> 6);
    if (n >= N) return;
    int lane = t & 63;
    int es = lane >> 2;        // edge slot 0..15
    int dg = lane & 3;         // dim group: uint2 = dims 4dg..4dg+3

    int e0 = row_ptr[n], e1 = row_ptr[n + 1];
    const uint2* rb = (const uint2*)h2u;     // row = 4 uint2

    float a0 = 0.f, a1 = 0.f, a2 = 0.f, a3 = 0.f;

    for (int base = e0 - 1; base < e1; base += 64) {
        int idx = base + lane;
        int sld = N;
        if (idx == e0 - 1) sld = n;
        else if (idx < e1) sld = csr_src[idx];
        int lim = e1 - base;
        int nr = (lim + 15) >> 4;                // rounds of 16
        nr = (nr + 1) & ~1;                      // even (extras hit row N)
        for (int r = 0; r < nr; r += 2) {
            int sA = __shfl(sld, (r << 4) + es);
            int sB = __shfl(sld, ((r + 1) << 4) + es);
            uint2 vA = rb[(size_t)sA * 4 + dg];
            uint2 vB = rb[(size_t)sB * 4 + dg];
            a0 += bflo(vA.x) + bflo(vB.x);
            a1 += bfhi(vA.x) + bfhi(vB.x);
            a2 += bflo(vA.y) + bflo(vB.y);
            a3 += bfhi(vA.y) + bfhi(vB.y);
        }
    }
    // reduce over edge slots (es stride 4 -> xor 4,8,16,32)
    #pragma unroll
    for (int m = 4; m <= 32; m <<= 1) {
        a0 += __shfl_xor(a0, m); a1 += __shfl_xor(a1, m);
        a2 += __shfl_xor(a2, m); a3 += __shfl_xor(a3, m);
    }
    if (es == 0) {
        float dn = dinv[n];
        float4 bb = ((const float4*)b2)[dg];
        float4 r;
        r.x = fmaf(dn, a0, bb.x);
        r.y = fmaf(dn, a1, bb.y);
        r.z = fmaf(dn, a2, bb.z);
        r.w = fmaf(dn, a3, bb.w);
        ((float4*)out)[(size_t)n * 4 + dg] = r;
    }
}

// ---------------------------------------------------------------------------
// Launch
// ---------------------------------------------------------------------------
extern "C" void kernel_launch(void* const* d_in, const int* in_sizes, int n_in,
                              void* d_out, int out_size, void* d_ws, size_t ws_size,
                              hipStream_t stream) {
    const float* x  = (const float*)d_in[0];
    const int*   ei = (const int*)d_in[1];
    const float* W1 = (const float*)d_in[2];
    const float* b1 = (const float*)d_in[3];
    const float* W2 = (const float*)d_in[4];
    const float* b2 = (const float*)d_in[5];
    float* out = (float*)d_out;

    const int N = in_sizes[0] / IN_DIM;   // 50000
    const int E = in_sizes[1] / 2;        // 1000000
    const int* src = ei;
    const int* dst = ei + E;

    const int NS  = (N + SMASK) >> SSHIFT;       // 391 stripes
    const int NSP = NS + 1;
    const int BC  = (E + CHUNK - 1) / CHUNK;     // 62 chunks (<= 64)

    char* w = (char*)d_ws;
    auto alloc = [&](size_t bytes) -> void* {
        void* p = (void*)w;
        w += (bytes + 255) & ~(size_t)255;
        return p;
    };
    int*      cm      = (int*)     alloc((size_t)BC * NSP * 4);
    int*      tot     = (int*)     alloc((size_t)NS * 4);
    int*      sbase   = (int*)     alloc((size_t)NS * 4);
    int*      eb      = (int*)     alloc((size_t)E * 4);
    int*      csr_src = (int*)     alloc((size_t)E * 4);
    int*      row_ptr = (int*)     alloc((size_t)(N + 1) * 4);
    float*    dinv    = (float*)   alloc((size_t)N * 4);
    unsigned* h1u     = (unsigned*)alloc((size_t)(N + 1) * 32 * 4);  // bf16 [N+1][64]
    unsigned* h1au    = (unsigned*)alloc((size_t)(N + 1) * 32 * 4);
    unsigned* h2u     = (unsigned*)alloc((size_t)(N + 1) * 8 * 4);   // bf16 [N+1][16]

    const int GB = (N + 16) / 16;    // covers rows 0..N (incl. dummy)
    const int AB = (N + 3) / 4;      // 4 nodes (waves) per block

    passA <<<BC, CBLK, 0, stream>>>(dst, cm, E, NS, NSP);
    passB1<<<NS, 64,   0, stream>>>(cm, tot, BC, NSP);
    passB2<<<1,  512,  0, stream>>>(tot, sbase, NS);
    passC <<<BC, CBLK, 0, stream>>>(src, dst, cm, sbase, eb, E, NS, NSP);
    passD <<<NS, 256,  0, stream>>>(eb, sbase, tot, csr_src, row_ptr, dinv, N, E, NS);

    gemm1_kernel<<<GB, 256, 0, stream>>>(x, W1, dinv, h1u, N);
    agg1_kernel<<<AB, 256, 0, stream>>>(h1u, row_ptr, csr_src, dinv, b1, h1au, N);
    gemm2_kernel<<<GB, 256, 0, stream>>>(h1au, W2, dinv, h2u, N);
    agg2_kernel<<<AB, 256, 0, stream>>>(h2u, row_ptr, csr_src, dinv, b2, out, N);
}